// Round 3
// baseline (845.193 us; speedup 1.0000x reference)
//
#include <hip/hip_runtime.h>
#include <hip/hip_bf16.h>

// GraphSAGE mean layer: out = relu(concat(x, mean_neigh(x)) @ W^T + b)
// N=50000 nodes, E=600000 edges, D=128 feat, 128 out.

constexpr int kD = 128;

// --- Phase 1: scatter-add features along edges + degree count -------------
// One wave (64 lanes) per edge. Lane i handles feature elements 2i, 2i+1.
__global__ __launch_bounds__(256) void sage_scatter(
    const int* __restrict__ ei,      // [2*E] (src row, then dst row)
    const float* __restrict__ feat,  // [N, 128]
    float* __restrict__ summed,      // [N, 128] (pre-zeroed)
    float* __restrict__ deg,         // [N]      (pre-zeroed)
    int E)
{
    const int gtid  = blockIdx.x * blockDim.x + threadIdx.x;
    const int wave  = gtid >> 6;
    const int lane  = threadIdx.x & 63;
    const int nwave = (gridDim.x * blockDim.x) >> 6;

    for (int e = wave; e < E; e += nwave) {
        const int s = ei[e];
        const int d = ei[E + e];
        const float2 v =
            *reinterpret_cast<const float2*>(feat + (size_t)s * kD + lane * 2);
        float* dp = summed + (size_t)d * kD + lane * 2;
        atomicAdd(dp,     v.x);
        atomicAdd(dp + 1, v.y);
        if (lane == 0) atomicAdd(deg + d, 1.0f);
    }
}

// --- Phase 2: [N,256] @ [256,128]^T + bias, relu --------------------------
// Block = 256 threads, handles 16 rows. Weight (bf16) + agg rows in LDS.
__global__ __launch_bounds__(256) void sage_gemm(
    const float* __restrict__ feat,    // [N,128]
    const float* __restrict__ summed,  // [N,128]
    const float* __restrict__ deg,     // [N]
    const float* __restrict__ weight,  // [128,256] row-major (o, d)
    const float* __restrict__ bias,    // [128]
    float* __restrict__ out,           // [N,128]
    int N)
{
    __shared__ __hip_bfloat16 w_lds[256][136];  // [d][o], padded
    __shared__ float agg[16][256];              // 16 rows x (feat | mean)

    const int t = threadIdx.x;

    // Stage weight (linear global read, bf16 convert).
    for (int i = t; i < 256 * 128; i += 256) {
        const int o = i >> 8;    // weight[o][d], i = o*256 + d
        const int d = i & 255;
        w_lds[d][o] = __float2bfloat16(weight[i]);
    }

    // Stage 16 rows of aggregated input: [feat(row) | summed(row)/max(deg,1)]
    const int row0 = blockIdx.x * 16;
    for (int i = t; i < 16 * 256; i += 256) {
        const int r = i >> 8;
        const int d = i & 255;
        const int row = row0 + r;
        float v = 0.0f;
        if (row < N) {
            if (d < 128) {
                v = feat[(size_t)row * kD + d];
            } else {
                const float dg = deg[row];
                v = summed[(size_t)row * kD + (d - 128)] / fmaxf(dg, 1.0f);
            }
        }
        agg[r][d] = v;
    }
    __syncthreads();

    // Each thread: one output column o, 8 rows.
    const int o     = t & 127;
    const int rbase = (t >> 7) * 8;   // 0 or 8

    float acc[8];
#pragma unroll
    for (int r = 0; r < 8; ++r) acc[r] = 0.0f;

    for (int d = 0; d < 256; d += 4) {
        const float w0 = __bfloat162float(w_lds[d + 0][o]);
        const float w1 = __bfloat162float(w_lds[d + 1][o]);
        const float w2 = __bfloat162float(w_lds[d + 2][o]);
        const float w3 = __bfloat162float(w_lds[d + 3][o]);
#pragma unroll
        for (int r = 0; r < 8; ++r) {
            const float4 a =
                *reinterpret_cast<const float4*>(&agg[rbase + r][d]);
            acc[r] = fmaf(a.x, w0, acc[r]);
            acc[r] = fmaf(a.y, w1, acc[r]);
            acc[r] = fmaf(a.z, w2, acc[r]);
            acc[r] = fmaf(a.w, w3, acc[r]);
        }
    }

    const float b = bias[o];
#pragma unroll
    for (int r = 0; r < 8; ++r) {
        const int row = row0 + rbase + r;
        if (row < N) {
            out[(size_t)row * kD + o] = fmaxf(acc[r] + b, 0.0f);
        }
    }
}

extern "C" void kernel_launch(void* const* d_in, const int* in_sizes, int n_in,
                              void* d_out, int out_size, void* d_ws, size_t ws_size,
                              hipStream_t stream) {
    // setup_inputs order: nodes(i64->int), edge_index(i64->int), features(f32),
    //                     weight(f32), bias(f32)
    const int*   ei     = (const int*)d_in[1];
    const float* feat   = (const float*)d_in[2];
    const float* weight = (const float*)d_in[3];
    const float* bias   = (const float*)d_in[4];
    float*       out    = (float*)d_out;

    const int E = in_sizes[1] / 2;
    const int N = in_sizes[2] / kD;

    float* summed = (float*)d_ws;
    float* deg    = summed + (size_t)N * kD;

    // Zero the scatter accumulators (ws is poisoned 0xAA before every launch).
    hipMemsetAsync(d_ws, 0, ((size_t)N * kD + N) * sizeof(float), stream);

    sage_scatter<<<8192, 256, 0, stream>>>(ei, feat, summed, deg, E);

    const int nblocks = (N + 15) / 16;
    sage_gemm<<<nblocks, 256, 0, stream>>>(feat, summed, deg, weight, bias, out, N);
}

// Round 6
// 369.596 us; speedup vs baseline: 2.2868x; 2.2868x over previous
//
#include <hip/hip_runtime.h>
#include <hip/hip_bf16.h>

// GraphSAGE mean layer on MI355X:
//   out = relu([x | mean_neigh(x)] @ W^T + b),  N=50000, E=600000, D=128.
// Structure: CSR build (hist/scan/fill) -> gather aggregation (no fp32
// atomics) -> bf16 MFMA GEMM with XOR-swizzled LDS.

constexpr int kD = 128;   // feature dim
constexpr int kK = 256;   // concat dim

typedef __attribute__((ext_vector_type(8))) short short8;
typedef __attribute__((ext_vector_type(4))) float f32x4;

__device__ inline unsigned f2bf(float f) {
    union { float f; unsigned u; } v; v.f = f;
    return (v.u + 0x7FFFu + ((v.u >> 16) & 1u)) >> 16;  // RNE bf16
}

// --- Phase A: in-degree histogram (int atomics, L2-resident) --------------
__global__ __launch_bounds__(256) void k_hist(const int* __restrict__ ei,
                                              int* cnt, int E) {
    const int e = blockIdx.x * 256 + threadIdx.x;
    if (e < E) atomicAdd(&cnt[ei[E + e]], 1);
}

// --- Phase B: exclusive scan of counts, single 1024-thread block ----------
// cursor holds counts on entry; on exit row_ptr = exclusive prefix,
// cursor = copy of row_ptr (fill cursors).
__global__ __launch_bounds__(1024) void k_scan(int* cursor, int* row_ptr, int N) {
    __shared__ int part[1024];
    const int t = threadIdx.x;
    const int chunk = (N + 1023) >> 10;
    int beg = t * chunk; if (beg > N) beg = N;
    int end = beg + chunk; if (end > N) end = N;
    int s = 0;
    for (int i = beg; i < end; ++i) s += cursor[i];
    part[t] = s;
    __syncthreads();
    for (int off = 1; off < 1024; off <<= 1) {
        const int v = (t >= off) ? part[t - off] : 0;
        __syncthreads();
        part[t] += v;
        __syncthreads();
    }
    int run = part[t] - s;  // exclusive prefix of this chunk
    for (int i = beg; i < end; ++i) {
        const int c = cursor[i];
        row_ptr[i] = run;
        cursor[i] = run;
        run += c;
    }
    if (t == 1023) row_ptr[N] = part[1023];
}

// --- Phase C: bin edges by destination ------------------------------------
__global__ __launch_bounds__(256) void k_fill(const int* __restrict__ ei,
                                              int* cursor, int* csr_src, int E) {
    const int e = blockIdx.x * 256 + threadIdx.x;
    if (e < E) {
        const int s = ei[e];
        const int d = ei[E + e];
        const int pos = atomicAdd(&cursor[d], 1);
        csr_src[pos] = s;
    }
}

// --- Phase D: gather aggregation, one wave per node -----------------------
// Lane i accumulates feature elements 2i, 2i+1 in registers; single writer.
__global__ __launch_bounds__(256) void k_agg(const int* __restrict__ csr_src,
                                             const int* __restrict__ row_ptr,
                                             const float* __restrict__ feat,
                                             __hip_bfloat16* __restrict__ meanb,
                                             int N) {
    const int node = blockIdx.x * 4 + (threadIdx.x >> 6);
    if (node >= N) return;
    const int lane = threadIdx.x & 63;
    const int beg = row_ptr[node];
    const int end = row_ptr[node + 1];
    float ax = 0.0f, ay = 0.0f;
    for (int j = beg; j < end; ++j) {
        const int s = csr_src[j];  // wave-uniform -> scalar load
        const float2 v =
            *reinterpret_cast<const float2*>(feat + (size_t)s * kD + lane * 2);
        ax += v.x; ay += v.y;
    }
    const float inv = 1.0f / fmaxf((float)(end - beg), 1.0f);
    const unsigned p = f2bf(ax * inv) | (f2bf(ay * inv) << 16);
    *reinterpret_cast<unsigned*>(meanb + (size_t)node * kD + lane * 2) = p;
}

// --- Phase E: out = relu([feat | mean] @ W^T + b), bf16 MFMA --------------
// Block = 256 thr (4 waves), 64 rows/block, 128 out cols.
// LDS tiles swizzled: byte = row*512 + (kb ^ ((row&7)<<4)) — spreads the
// stride-512B column reads over all 8 16B slot-groups (b128 floor).
__global__ __launch_bounds__(256) void k_gemm(
    const float* __restrict__ feat,            // [N,128] f32
    const __hip_bfloat16* __restrict__ meanb,  // [N,128] bf16
    const float* __restrict__ weight,          // [128,256] f32 (o, k)
    const float* __restrict__ bias,            // [128]
    float* __restrict__ out,                   // [N,128]
    int N)
{
    __shared__ char w_lds[128 * 512];  // 128 out-rows x 256 k bf16 (64 KB)
    __shared__ char a_lds[64 * 512];   // 64 rows x 256 k bf16 (32 KB)

    const int t = threadIdx.x;
    const int row0 = blockIdx.x * 64;

    // Stage W (f32 -> bf16), 4096 x 16B granules.
    for (int it = 0; it < 16; ++it) {
        const int gid = it * 256 + t;
        const int r = gid >> 5;          // out row 0..127
        const int kb = (gid & 31) * 16;  // byte offset within bf16 row
        const int k0 = kb >> 1;          // k element index
        const float4 lo = *reinterpret_cast<const float4*>(weight + r * kK + k0);
        const float4 hi = *reinterpret_cast<const float4*>(weight + r * kK + k0 + 4);
        uint4 p;
        p.x = f2bf(lo.x) | (f2bf(lo.y) << 16);
        p.y = f2bf(lo.z) | (f2bf(lo.w) << 16);
        p.z = f2bf(hi.x) | (f2bf(hi.y) << 16);
        p.w = f2bf(hi.z) | (f2bf(hi.w) << 16);
        *reinterpret_cast<uint4*>(w_lds + r * 512 + (kb ^ ((r & 7) << 4))) = p;
    }

    // Stage A rows: [feat(row) | mean(row)], 2048 x 16B granules.
    for (int it = 0; it < 8; ++it) {
        const int gid = it * 256 + t;
        const int r = gid >> 5;        // local row 0..63
        const int slot = gid & 31;     // 16B granule within row (k = slot*8)
        const int row = row0 + r;
        uint4 p = {0u, 0u, 0u, 0u};
        if (row < N) {
            if (slot < 16) {
                const int k0 = slot * 8;
                const float4 lo =
                    *reinterpret_cast<const float4*>(feat + (size_t)row * kD + k0);
                const float4 hi =
                    *reinterpret_cast<const float4*>(feat + (size_t)row * kD + k0 + 4);
                p.x = f2bf(lo.x) | (f2bf(lo.y) << 16);
                p.y = f2bf(lo.z) | (f2bf(lo.w) << 16);
                p.z = f2bf(hi.x) | (f2bf(hi.y) << 16);
                p.w = f2bf(hi.z) | (f2bf(hi.w) << 16);
            } else {
                p = *reinterpret_cast<const uint4*>(
                        meanb + (size_t)row * kD + (slot - 16) * 8);
            }
        }
        const int kb = slot * 16;
        *reinterpret_cast<uint4*>(a_lds + r * 512 + (kb ^ ((r & 7) << 4))) = p;
    }
    __syncthreads();

    const int lane = t & 63;
    const int wave = t >> 6;
    const int fr = lane & 15;   // fragment row (A) / col (B)
    const int kq = lane >> 4;   // k-quad: lane holds k = ks*32 + kq*8 .. +7

    f32x4 acc[8];
#pragma unroll
    for (int i = 0; i < 8; ++i) acc[i] = {0.f, 0.f, 0.f, 0.f};

    const int ar = wave * 16 + fr;  // local A row
#pragma unroll
    for (int ks = 0; ks < 8; ++ks) {
        const int kb = ks * 64 + kq * 16;
        const short8 a = *reinterpret_cast<const short8*>(
            a_lds + ar * 512 + (kb ^ ((ar & 7) << 4)));
#pragma unroll
        for (int bt = 0; bt < 8; ++bt) {
            const int wr = bt * 16 + fr;  // W row = output col
            const short8 b = *reinterpret_cast<const short8*>(
                w_lds + wr * 512 + (kb ^ ((wr & 7) << 4)));
            acc[bt] = __builtin_amdgcn_mfma_f32_16x16x32_bf16(a, b, acc[bt], 0, 0, 0);
        }
    }

    // C/D layout: col = lane&15, row = (lane>>4)*4 + reg  [m89]
#pragma unroll
    for (int bt = 0; bt < 8; ++bt) {
        const int col = bt * 16 + fr;
        const float bs = bias[col];
#pragma unroll
        for (int i = 0; i < 4; ++i) {
            const int row = row0 + wave * 16 + kq * 4 + i;
            if (row < N) out[(size_t)row * kD + col] = fmaxf(acc[bt][i] + bs, 0.0f);
        }
    }
}

extern "C" void kernel_launch(void* const* d_in, const int* in_sizes, int n_in,
                              void* d_out, int out_size, void* d_ws, size_t ws_size,
                              hipStream_t stream) {
    // inputs: nodes(unused), edge_index(int), features(f32), weight(f32), bias(f32)
    const int*   ei     = (const int*)d_in[1];
    const float* feat   = (const float*)d_in[2];
    const float* weight = (const float*)d_in[3];
    const float* bias   = (const float*)d_in[4];
    float*       out    = (float*)d_out;

    const int E = in_sizes[1] / 2;
    const int N = in_sizes[2] / kD;

    // workspace: mean_bf16 [N*128] | row_ptr [N+1] | cursor [N] | csr_src [E]
    __hip_bfloat16* meanb = (__hip_bfloat16*)d_ws;
    int* row_ptr = (int*)(meanb + (size_t)N * kD);
    int* cursor  = row_ptr + (N + 1);
    int* csr_src = cursor + N;

    hipMemsetAsync(cursor, 0, (size_t)N * sizeof(int), stream);

    const int eb = (E + 255) / 256;
    k_hist<<<eb, 256, 0, stream>>>(ei, cursor, E);
    k_scan<<<1, 1024, 0, stream>>>(cursor, row_ptr, N);
    k_fill<<<eb, 256, 0, stream>>>(ei, cursor, csr_src, E);
    k_agg<<<(N + 3) / 4, 256, 0, stream>>>(csr_src, row_ptr, feat, meanb, N);
    k_gemm<<<(N + 63) / 64, 256, 0, stream>>>(feat, meanb, weight, bias, out, N);
}

// Round 7
// 254.407 us; speedup vs baseline: 3.3222x; 1.4528x over previous
//
#include <hip/hip_runtime.h>
#include <hip/hip_bf16.h>

// GraphSAGE mean layer on MI355X:
//   out = relu([x | mean_neigh(x)] @ W^T + b),  N=50000, E=600000, D=128.
// CSR build (hist / 3-kernel parallel scan / fill) -> bf16 gather-mean
// -> bf16 MFMA GEMM with XOR-swizzled LDS.

constexpr int kD = 128;   // feature dim
constexpr int kK = 256;   // concat dim

typedef __attribute__((ext_vector_type(8))) short short8;
typedef __attribute__((ext_vector_type(4))) float f32x4;

__device__ inline unsigned f2bf(float f) {
    union { float f; unsigned u; } v; v.f = f;
    return (v.u + 0x7FFFu + ((v.u >> 16) & 1u)) >> 16;  // RNE bf16
}
__device__ inline float bf2f(unsigned h) {
    union { unsigned u; float f; } v; v.u = h << 16;
    return v.f;
}

// --- feat f32 -> bf16 into aggb[n][0:128] ---------------------------------
__global__ __launch_bounds__(256) void k_cvt(const float* __restrict__ feat,
                                             __hip_bfloat16* __restrict__ aggb,
                                             int total /* N*16 granules */) {
    const int gid = blockIdx.x * 256 + threadIdx.x;
    if (gid >= total) return;
    const int row = gid >> 4;
    const int slot = gid & 15;            // 8-elem granule within 128
    const float4 lo = *reinterpret_cast<const float4*>(feat + (size_t)row * kD + slot * 8);
    const float4 hi = *reinterpret_cast<const float4*>(feat + (size_t)row * kD + slot * 8 + 4);
    uint4 p;
    p.x = f2bf(lo.x) | (f2bf(lo.y) << 16);
    p.y = f2bf(lo.z) | (f2bf(lo.w) << 16);
    p.z = f2bf(hi.x) | (f2bf(hi.y) << 16);
    p.w = f2bf(hi.z) | (f2bf(hi.w) << 16);
    *reinterpret_cast<uint4*>(aggb + (size_t)row * kK + slot * 8) = p;
}

// --- in-degree histogram ---------------------------------------------------
__global__ __launch_bounds__(256) void k_hist(const int* __restrict__ ei,
                                              int* cnt, int E) {
    const int e = blockIdx.x * 256 + threadIdx.x;
    if (e < E) atomicAdd(&cnt[ei[E + e]], 1);
}

// --- parallel exclusive scan: per-block reduce ----------------------------
__global__ __launch_bounds__(256) void k_scan_part(const int* __restrict__ cnt,
                                                   int* bsum, int N) {
    __shared__ int red[256];
    const int t = threadIdx.x;
    const int i = blockIdx.x * 256 + t;
    red[t] = (i < N) ? cnt[i] : 0;
    __syncthreads();
    for (int off = 128; off > 0; off >>= 1) {
        if (t < off) red[t] += red[t + off];
        __syncthreads();
    }
    if (t == 0) bsum[blockIdx.x] = red[0];
}

// --- scan the block sums (NB <= 256), in place, exclusive -----------------
__global__ __launch_bounds__(256) void k_scan_mid(int* bsum, int NB) {
    __shared__ int s[256];
    const int t = threadIdx.x;
    const int v = (t < NB) ? bsum[t] : 0;
    s[t] = v;
    __syncthreads();
    for (int off = 1; off < 256; off <<= 1) {
        const int u = (t >= off) ? s[t - off] : 0;
        __syncthreads();
        s[t] += u;
        __syncthreads();
    }
    if (t < NB) bsum[t] = s[t] - v;  // exclusive
}

// --- local scan + block offset; writes row_ptr and fill cursors -----------
__global__ __launch_bounds__(256) void k_scan_add(int* __restrict__ cursor,
                                                  const int* __restrict__ bsum,
                                                  int* __restrict__ row_ptr,
                                                  int N) {
    __shared__ int s[256];
    const int t = threadIdx.x;
    const int i = blockIdx.x * 256 + t;
    const int v = (i < N) ? cursor[i] : 0;
    s[t] = v;
    __syncthreads();
    for (int off = 1; off < 256; off <<= 1) {
        const int u = (t >= off) ? s[t - off] : 0;
        __syncthreads();
        s[t] += u;
        __syncthreads();
    }
    const int excl = s[t] - v + bsum[blockIdx.x];
    if (i < N) {
        row_ptr[i] = excl;
        cursor[i] = excl;   // fill cursor (overwrites count; per-thread RAW ok)
        if (i == N - 1) row_ptr[N] = excl + v;
    }
}

// --- bin edges by destination ---------------------------------------------
__global__ __launch_bounds__(256) void k_fill(const int* __restrict__ ei,
                                              int* cursor, int* csr_src, int E) {
    const int e = blockIdx.x * 256 + threadIdx.x;
    if (e < E) {
        const int s = ei[e];
        const int d = ei[E + e];
        const int pos = atomicAdd(&cursor[d], 1);
        csr_src[pos] = s;
    }
}

// --- gather-mean, one wave per node; bf16 reads, fp32 accum ---------------
// Lane i handles elements 2i, 2i+1 (one dword of 2 bf16 per neighbor row).
__global__ __launch_bounds__(256) void k_agg(const int* __restrict__ csr_src,
                                             const int* __restrict__ row_ptr,
                                             __hip_bfloat16* __restrict__ aggb,
                                             int N) {
    const int node = blockIdx.x * 4 + (threadIdx.x >> 6);
    if (node >= N) return;
    const int lane = threadIdx.x & 63;
    const int beg = row_ptr[node];
    const int end = row_ptr[node + 1];
    float ax = 0.0f, ay = 0.0f;
    for (int j = beg; j < end; ++j) {
        const int s = csr_src[j];  // wave-uniform -> scalar load
        const unsigned v = *reinterpret_cast<const unsigned*>(
            aggb + (size_t)s * kK + lane * 2);
        ax += bf2f(v & 0xFFFFu);
        ay += bf2f(v >> 16);
    }
    const float inv = 1.0f / fmaxf((float)(end - beg), 1.0f);
    const unsigned p = f2bf(ax * inv) | (f2bf(ay * inv) << 16);
    *reinterpret_cast<unsigned*>(aggb + (size_t)node * kK + kD + lane * 2) = p;
}

// --- out = relu(aggb @ W^T + b), bf16 MFMA --------------------------------
// Block = 256 thr (4 waves), 64 rows/block, 128 out cols.
// LDS swizzle: byte = row*512 + (kb ^ ((row&7)<<4)).
__global__ __launch_bounds__(256) void k_gemm(
    const __hip_bfloat16* __restrict__ aggb,   // [N,256] bf16
    const float* __restrict__ weight,          // [128,256] f32 (o, k)
    const float* __restrict__ bias,            // [128]
    float* __restrict__ out,                   // [N,128]
    int N)
{
    __shared__ char w_lds[128 * 512];  // 128 out-rows x 256 k bf16 (64 KB)
    __shared__ char a_lds[64 * 512];   // 64 rows x 256 k bf16 (32 KB)

    const int t = threadIdx.x;
    const int row0 = blockIdx.x * 64;

    // Stage W (f32 -> bf16), 4096 x 16B granules.
    for (int it = 0; it < 16; ++it) {
        const int gid = it * 256 + t;
        const int r = gid >> 5;          // out row 0..127
        const int kb = (gid & 31) * 16;  // byte offset within bf16 row
        const int k0 = kb >> 1;
        const float4 lo = *reinterpret_cast<const float4*>(weight + r * kK + k0);
        const float4 hi = *reinterpret_cast<const float4*>(weight + r * kK + k0 + 4);
        uint4 p;
        p.x = f2bf(lo.x) | (f2bf(lo.y) << 16);
        p.y = f2bf(lo.z) | (f2bf(lo.w) << 16);
        p.z = f2bf(hi.x) | (f2bf(hi.y) << 16);
        p.w = f2bf(hi.z) | (f2bf(hi.w) << 16);
        *reinterpret_cast<uint4*>(w_lds + r * 512 + (kb ^ ((r & 7) << 4))) = p;
    }

    // Stage A rows straight from aggb (bf16), 2048 x 16B granules.
    for (int it = 0; it < 8; ++it) {
        const int gid = it * 256 + t;
        const int r = gid >> 5;        // local row 0..63
        const int slot = gid & 31;     // 16B granule (8 bf16)
        const int row = row0 + r;
        uint4 p = {0u, 0u, 0u, 0u};
        if (row < N)
            p = *reinterpret_cast<const uint4*>(aggb + (size_t)row * kK + slot * 8);
        const int kb = slot * 16;
        *reinterpret_cast<uint4*>(a_lds + r * 512 + (kb ^ ((r & 7) << 4))) = p;
    }
    __syncthreads();

    const int lane = t & 63;
    const int wave = t >> 6;
    const int fr = lane & 15;   // fragment row (A) / col (B)
    const int kq = lane >> 4;   // k-quad

    f32x4 acc[8];
#pragma unroll
    for (int i = 0; i < 8; ++i) acc[i] = {0.f, 0.f, 0.f, 0.f};

    const int ar = wave * 16 + fr;
#pragma unroll
    for (int ks = 0; ks < 8; ++ks) {
        const int kb = ks * 64 + kq * 16;
        const short8 a = *reinterpret_cast<const short8*>(
            a_lds + ar * 512 + (kb ^ ((ar & 7) << 4)));
#pragma unroll
        for (int bt = 0; bt < 8; ++bt) {
            const int wr = bt * 16 + fr;  // W row = output col
            const short8 b = *reinterpret_cast<const short8*>(
                w_lds + wr * 512 + (kb ^ ((wr & 7) << 4)));
            acc[bt] = __builtin_amdgcn_mfma_f32_16x16x32_bf16(a, b, acc[bt], 0, 0, 0);
        }
    }

    // C/D layout: col = lane&15, row = (lane>>4)*4 + reg  [m89]
#pragma unroll
    for (int bt = 0; bt < 8; ++bt) {
        const int col = bt * 16 + fr;
        const float bs = bias[col];
#pragma unroll
        for (int i = 0; i < 4; ++i) {
            const int row = row0 + wave * 16 + kq * 4 + i;
            if (row < N) out[(size_t)row * kD + col] = fmaxf(acc[bt][i] + bs, 0.0f);
        }
    }
}

extern "C" void kernel_launch(void* const* d_in, const int* in_sizes, int n_in,
                              void* d_out, int out_size, void* d_ws, size_t ws_size,
                              hipStream_t stream) {
    // inputs: nodes(unused), edge_index(int), features(f32), weight(f32), bias(f32)
    const int*   ei     = (const int*)d_in[1];
    const float* feat   = (const float*)d_in[2];
    const float* weight = (const float*)d_in[3];
    const float* bias   = (const float*)d_in[4];
    float*       out    = (float*)d_out;

    const int E = in_sizes[1] / 2;
    const int N = in_sizes[2] / kD;

    // ws: aggb bf16 [N*256] | row_ptr [N+1] | cursor [N] | csr_src [E] | bsum [256]
    __hip_bfloat16* aggb = (__hip_bfloat16*)d_ws;
    int* row_ptr = (int*)(aggb + (size_t)N * kK);
    int* cursor  = row_ptr + (N + 1);
    int* csr_src = cursor + N;
    int* bsum    = csr_src + E;

    hipMemsetAsync(cursor, 0, (size_t)N * sizeof(int), stream);

    const int eb = (E + 255) / 256;
    const int NB = (N + 255) / 256;   // 196 <= 256

    k_hist<<<eb, 256, 0, stream>>>(ei, cursor, E);
    k_scan_part<<<NB, 256, 0, stream>>>(cursor, bsum, N);
    k_scan_mid<<<1, 256, 0, stream>>>(bsum, NB);
    k_scan_add<<<NB, 256, 0, stream>>>(cursor, bsum, row_ptr, N);
    k_cvt<<<(N * 16 + 255) / 256, 256, 0, stream>>>(feat, aggb, N * 16);
    k_fill<<<eb, 256, 0, stream>>>(ei, cursor, csr_src, E);
    k_agg<<<(N + 3) / 4, 256, 0, stream>>>(csr_src, row_ptr, aggb, N);
    k_gemm<<<(N + 63) / 64, 256, 0, stream>>>(aggb, weight, bias, out, N);
}

// Round 8
// 201.401 us; speedup vs baseline: 4.1966x; 1.2632x over previous
//
#include <hip/hip_runtime.h>
#include <hip/hip_bf16.h>

// GraphSAGE mean layer on MI355X:
//   out = relu([x | mean_neigh(x)] @ W^T + b),  N=50000, E=600000, D=128.
// prep(hist + feat->bf16 + W->bf16-frag) -> parallel scan -> fill ->
// gather-mean (4 neighbors/iter, 16B/lane) -> bf16 MFMA GEMM (128 rows/blk).

constexpr int kD = 128;   // feature dim
constexpr int kK = 256;   // concat dim

typedef __attribute__((ext_vector_type(8))) short short8;
typedef __attribute__((ext_vector_type(4))) float f32x4;

__device__ inline unsigned f2bf(float f) {
    union { float f; unsigned u; } v; v.f = f;
    return (v.u + 0x7FFFu + ((v.u >> 16) & 1u)) >> 16;  // RNE bf16
}
__device__ inline float bf2f_lo(unsigned u) {
    union { unsigned u; float f; } v; v.u = u << 16; return v.f;
}
__device__ inline float bf2f_hi(unsigned u) {
    union { unsigned u; float f; } v; v.u = u & 0xFFFF0000u; return v.f;
}

// --- fused prep: [0,eb) hist | [eb,eb+cvtb) feat cvt | rest: W cvt --------
__global__ __launch_bounds__(256) void k_prep(
    const int* __restrict__ ei, int* cnt,
    const float* __restrict__ feat, __hip_bfloat16* __restrict__ aggb,
    const float* __restrict__ weight, __hip_bfloat16* __restrict__ wfrag,
    int E, int N, int eb, int cvtb)
{
    const int bid = blockIdx.x;
    const int t = threadIdx.x;
    if (bid < eb) {
        const int e = bid * 256 + t;
        if (e < E) atomicAdd(&cnt[ei[E + e]], 1);
    } else if (bid < eb + cvtb) {
        const int gid = (bid - eb) * 256 + t;      // granule over N*16
        if (gid >= N * 16) return;
        const int row = gid >> 4;
        const int slot = gid & 15;                 // 8-elem granule in 128
        const float4 lo = *reinterpret_cast<const float4*>(feat + (size_t)row * kD + slot * 8);
        const float4 hi = *reinterpret_cast<const float4*>(feat + (size_t)row * kD + slot * 8 + 4);
        uint4 p;
        p.x = f2bf(lo.x) | (f2bf(lo.y) << 16);
        p.y = f2bf(lo.z) | (f2bf(lo.w) << 16);
        p.z = f2bf(hi.x) | (f2bf(hi.y) << 16);
        p.w = f2bf(hi.z) | (f2bf(hi.w) << 16);
        *reinterpret_cast<uint4*>(aggb + (size_t)row * kK + slot * 8) = p;
    } else {
        // W -> bf16 in MFMA B-fragment order:
        // granule gd = (bt*8+ks)*64 + (kq*16+fr) holds W[bt*16+fr][ks*32+kq*8 ..+8)
        const int gd = (bid - eb - cvtb) * 256 + t;    // 0..4095
        if (gd >= 4096) return;
        const int fr = gd & 15;
        const int kq = (gd >> 4) & 3;
        const int ks = (gd >> 6) & 7;
        const int bt = gd >> 9;
        const int o  = bt * 16 + fr;
        const int k0 = ks * 32 + kq * 8;
        const float4 lo = *reinterpret_cast<const float4*>(weight + o * kK + k0);
        const float4 hi = *reinterpret_cast<const float4*>(weight + o * kK + k0 + 4);
        uint4 p;
        p.x = f2bf(lo.x) | (f2bf(lo.y) << 16);
        p.y = f2bf(lo.z) | (f2bf(lo.w) << 16);
        p.z = f2bf(hi.x) | (f2bf(hi.y) << 16);
        p.w = f2bf(hi.z) | (f2bf(hi.w) << 16);
        *reinterpret_cast<uint4*>(wfrag + (size_t)gd * 8) = p;
    }
}

// --- parallel exclusive scan: per-block reduce ----------------------------
__global__ __launch_bounds__(256) void k_scan_part(const int* __restrict__ cnt,
                                                   int* bsum, int N) {
    __shared__ int red[256];
    const int t = threadIdx.x;
    const int i = blockIdx.x * 256 + t;
    red[t] = (i < N) ? cnt[i] : 0;
    __syncthreads();
    for (int off = 128; off > 0; off >>= 1) {
        if (t < off) red[t] += red[t + off];
        __syncthreads();
    }
    if (t == 0) bsum[blockIdx.x] = red[0];
}

__global__ __launch_bounds__(256) void k_scan_mid(int* bsum, int NB) {
    __shared__ int s[256];
    const int t = threadIdx.x;
    const int v = (t < NB) ? bsum[t] : 0;
    s[t] = v;
    __syncthreads();
    for (int off = 1; off < 256; off <<= 1) {
        const int u = (t >= off) ? s[t - off] : 0;
        __syncthreads();
        s[t] += u;
        __syncthreads();
    }
    if (t < NB) bsum[t] = s[t] - v;  // exclusive
}

__global__ __launch_bounds__(256) void k_scan_add(int* __restrict__ cursor,
                                                  const int* __restrict__ bsum,
                                                  int* __restrict__ row_ptr,
                                                  int N) {
    __shared__ int s[256];
    const int t = threadIdx.x;
    const int i = blockIdx.x * 256 + t;
    const int v = (i < N) ? cursor[i] : 0;
    s[t] = v;
    __syncthreads();
    for (int off = 1; off < 256; off <<= 1) {
        const int u = (t >= off) ? s[t - off] : 0;
        __syncthreads();
        s[t] += u;
        __syncthreads();
    }
    const int excl = s[t] - v + bsum[blockIdx.x];
    if (i < N) {
        row_ptr[i] = excl;
        cursor[i] = excl;
        if (i == N - 1) row_ptr[N] = excl + v;
    }
}

// --- bin edges by destination ---------------------------------------------
__global__ __launch_bounds__(256) void k_fill(const int* __restrict__ ei,
                                              int* cursor, int* csr_src, int E) {
    const int e = blockIdx.x * 256 + threadIdx.x;
    if (e < E) {
        const int s = ei[e];
        const int d = ei[E + e];
        const int pos = atomicAdd(&cursor[d], 1);
        csr_src[pos] = s;
    }
}

// --- gather-mean: one wave/node, 4 neighbors x 16B per iteration ----------
// lane = (g, c): g = neighbor subslot (lane>>4), c = 16B chunk (lane&15).
__global__ __launch_bounds__(256) void k_agg(const int* __restrict__ csr_src,
                                             const int* __restrict__ row_ptr,
                                             __hip_bfloat16* __restrict__ aggb,
                                             int N) {
    const int node = blockIdx.x * 4 + (threadIdx.x >> 6);
    if (node >= N) return;
    const int lane = threadIdx.x & 63;
    const int g = lane >> 4;
    const int c = lane & 15;
    const int beg = row_ptr[node];
    const int end = row_ptr[node + 1];

    float s8[8];
#pragma unroll
    for (int i = 0; i < 8; ++i) s8[i] = 0.0f;

    // software-pipelined: prefetch next iteration's neighbor index
    int jn = beg + g;
    int sn = (jn < end) ? csr_src[jn] : -1;
    for (int j0 = beg; j0 < end; j0 += 4) {
        const int s = sn;
        const int j2 = j0 + 4 + g;
        sn = (j2 < end) ? csr_src[j2] : -1;
        if (s >= 0) {
            const uint4 v = *reinterpret_cast<const uint4*>(
                aggb + (size_t)s * kK + c * 8);
            s8[0] += bf2f_lo(v.x); s8[1] += bf2f_hi(v.x);
            s8[2] += bf2f_lo(v.y); s8[3] += bf2f_hi(v.y);
            s8[4] += bf2f_lo(v.z); s8[5] += bf2f_hi(v.z);
            s8[6] += bf2f_lo(v.w); s8[7] += bf2f_hi(v.w);
        }
    }

    // reduce across g (lanes ^16, ^32)
#pragma unroll
    for (int i = 0; i < 8; ++i) {
        s8[i] += __shfl_xor(s8[i], 16, 64);
        s8[i] += __shfl_xor(s8[i], 32, 64);
    }

    if (g == 0) {
        const float inv = 1.0f / fmaxf((float)(end - beg), 1.0f);
        uint4 p;
        p.x = f2bf(s8[0] * inv) | (f2bf(s8[1] * inv) << 16);
        p.y = f2bf(s8[2] * inv) | (f2bf(s8[3] * inv) << 16);
        p.z = f2bf(s8[4] * inv) | (f2bf(s8[5] * inv) << 16);
        p.w = f2bf(s8[6] * inv) | (f2bf(s8[7] * inv) << 16);
        *reinterpret_cast<uint4*>(aggb + (size_t)node * kK + kD + c * 8) = p;
    }
}

// --- out = relu(aggb @ W^T + b): 512 thr, 128 rows/block ------------------
// W in LDS = linear copy of fragment-major wfrag (conflict-free lane*16
// reads). A in LDS row-major with XOR swizzle (row&7)<<4.
__global__ __launch_bounds__(512) void k_gemm(
    const __hip_bfloat16* __restrict__ aggb,   // [N,256] bf16
    const __hip_bfloat16* __restrict__ wfrag,  // [4096*8] bf16 frag-major
    const float* __restrict__ bias,            // [128]
    float* __restrict__ out,                   // [N,128]
    int N)
{
    __shared__ char w_lds[64 * 1024];   // 64 KB: frag-major W
    __shared__ char a_lds[128 * 512];   // 64 KB: 128 rows x 256 k bf16

    const int t = threadIdx.x;
    const int row0 = blockIdx.x * 128;

    // Stage W: linear 64KB copy (4096 granules / 512 thr = 8 iters).
#pragma unroll
    for (int it = 0; it < 8; ++it) {
        const int gd = it * 512 + t;
        *reinterpret_cast<uint4*>(w_lds + gd * 16) =
            *reinterpret_cast<const uint4*>(wfrag + (size_t)gd * 8);
    }

    // Stage A rows (bf16), 4096 granules.
#pragma unroll
    for (int it = 0; it < 8; ++it) {
        const int gid = it * 512 + t;
        const int r = gid >> 5;        // local row 0..127
        const int slot = gid & 31;     // 16B granule
        const int row = row0 + r;
        uint4 p = {0u, 0u, 0u, 0u};
        if (row < N)
            p = *reinterpret_cast<const uint4*>(aggb + (size_t)row * kK + slot * 8);
        const int kb = slot * 16;
        *reinterpret_cast<uint4*>(a_lds + r * 512 + (kb ^ ((r & 7) << 4))) = p;
    }
    __syncthreads();

    const int lane = t & 63;
    const int w = t >> 6;       // wave 0..7 -> rows w*16..w*16+15
    const int fr = lane & 15;
    const int kq = lane >> 4;

    f32x4 acc[8];
#pragma unroll
    for (int i = 0; i < 8; ++i) acc[i] = {0.f, 0.f, 0.f, 0.f};

    const int ar = w * 16 + fr;
#pragma unroll
    for (int ks = 0; ks < 8; ++ks) {
        const int kb = ks * 64 + kq * 16;
        const short8 a = *reinterpret_cast<const short8*>(
            a_lds + ar * 512 + (kb ^ ((ar & 7) << 4)));
#pragma unroll
        for (int bt = 0; bt < 8; ++bt) {
            const short8 b = *reinterpret_cast<const short8*>(
                w_lds + ((bt * 8 + ks) * 64 + lane) * 16);
            acc[bt] = __builtin_amdgcn_mfma_f32_16x16x32_bf16(a, b, acc[bt], 0, 0, 0);
        }
    }

    // C/D layout: col = lane&15, row = (lane>>4)*4 + reg  [m89]
#pragma unroll
    for (int bt = 0; bt < 8; ++bt) {
        const int col = bt * 16 + fr;
        const float bs = bias[col];
#pragma unroll
        for (int i = 0; i < 4; ++i) {
            const int row = row0 + w * 16 + kq * 4 + i;
            if (row < N) out[(size_t)row * kD + col] = fmaxf(acc[bt][i] + bs, 0.0f);
        }
    }
}

extern "C" void kernel_launch(void* const* d_in, const int* in_sizes, int n_in,
                              void* d_out, int out_size, void* d_ws, size_t ws_size,
                              hipStream_t stream) {
    // inputs: nodes(unused), edge_index(int), features(f32), weight(f32), bias(f32)
    const int*   ei     = (const int*)d_in[1];
    const float* feat   = (const float*)d_in[2];
    const float* weight = (const float*)d_in[3];
    const float* bias   = (const float*)d_in[4];
    float*       out    = (float*)d_out;

    const int E = in_sizes[1] / 2;
    const int N = in_sizes[2] / kD;

    // ws: aggb bf16 [N*256] | wfrag bf16 [32768] | row_ptr [N+1] | cursor [N]
    //     | csr_src [E] | bsum [256]
    __hip_bfloat16* aggb  = (__hip_bfloat16*)d_ws;
    __hip_bfloat16* wfrag = aggb + (size_t)N * kK;
    int* row_ptr = (int*)(wfrag + 32768);
    int* cursor  = row_ptr + (N + 1);
    int* csr_src = cursor + N;
    int* bsum    = csr_src + E;

    hipMemsetAsync(cursor, 0, (size_t)N * sizeof(int), stream);

    const int eb   = (E + 255) / 256;
    const int cvtb = (N * 16 + 255) / 256;
    const int wb   = 16;
    const int NB   = (N + 255) / 256;   // 196 <= 256

    k_prep<<<eb + cvtb + wb, 256, 0, stream>>>(ei, cursor, feat, aggb,
                                               weight, wfrag, E, N, eb, cvtb);
    k_scan_part<<<NB, 256, 0, stream>>>(cursor, bsum, N);
    k_scan_mid<<<1, 256, 0, stream>>>(bsum, NB);
    k_scan_add<<<NB, 256, 0, stream>>>(cursor, bsum, row_ptr, N);
    k_fill<<<eb, 256, 0, stream>>>(ei, cursor, csr_src, E);
    k_agg<<<(N + 3) / 4, 256, 0, stream>>>(csr_src, row_ptr, aggb, N);
    k_gemm<<<(N + 127) / 128, 512, 0, stream>>>(aggb, wfrag, bias, out, N);
}